// Round 1
// baseline (237.856 us; speedup 1.0000x reference)
//
#include <hip/hip_runtime.h>
#include <hip/hip_bf16.h>
#include <cstddef>
#include <cstdint>

// SelfAttn (SAGAN) — Round 6: PV double-buffered (16 chunks of 64p, stage c+1
// overlapped with compute c, 1 barrier/chunk) + s_setprio around MFMA clusters.
// pack -> proj GEMM [32768x384] -> pools -> fused attn -> out GEMM(+resid)

typedef __attribute__((ext_vector_type(8))) short short8;
typedef __attribute__((ext_vector_type(4))) float float4v;

namespace {
constexpr int kB = 8, kC = 512, kCK = 64, kCV = 256, kHW = 4096, kP = 1024;
constexpr int kNP = 384;  // packed projection width [theta|phi|g]
}

__device__ __forceinline__ void gll16(const void* g, void* l) {
  __builtin_amdgcn_global_load_lds((uint32_t __attribute__((address_space(1)))*)g,
                                   (uint32_t __attribute__((address_space(3)))*)l,
                                   16, 0, 0);
}
__device__ __forceinline__ float4v mfma16(short8 a, short8 b, float4v c) {
  return __builtin_amdgcn_mfma_f32_16x16x32_bf16(a, b, c, 0, 0, 0);
}
// bf16 tile row = 128B (8 octs of 16B), slot swizzle oct ^ (row&7)
__device__ __forceinline__ const short8* fragp(const char* tile, int row, int oct) {
  return (const short8*)(tile + row * 128 + ((oct ^ (row & 7)) * 16));
}
// bf16 tile row = 256B (16 octs of 16B), slot swizzle oct ^ (row&15)
__device__ __forceinline__ const short8* fragp16(const char* tile, int row, int oct) {
  return (const short8*)(tile + row * 256 + ((oct ^ (row & 15)) * 16));
}

// pack weights: wAll[384][512] = [theta|phi|g]^T; woT[512][256]
__global__ __launch_bounds__(256) void k_pack_w(
    const float* __restrict__ wt, const float* __restrict__ wphi,
    const float* __restrict__ wg, const float* __restrict__ wo,
    __hip_bfloat16* __restrict__ wAll, __hip_bfloat16* __restrict__ woT) {
  int idx = blockIdx.x * 256 + threadIdx.x;  // 327680
  if (idx < 196608) {
    int n = idx >> 9, k = idx & 511;
    float v = (n < 64) ? wt[k * 64 + n]
            : (n < 128) ? wphi[k * 64 + (n - 64)]
                        : wg[k * 256 + (n - 128)];
    wAll[idx] = __float2bfloat16(v);
  } else {
    int t = idx - 196608;
    int n = t >> 8, k = t & 255;
    woT[t] = __float2bfloat16(wo[k * 512 + n]);
  }
}

// ---- proj: pgf[32768][384] = bf16(x) @ wAll^T, A fp32 read direct, tile 64x384 ----
__global__ __launch_bounds__(256) void k_proj(const float* __restrict__ x,
                                              const __hip_bfloat16* __restrict__ wAll,
                                              __hip_bfloat16* __restrict__ pgf) {
  __shared__ __align__(16) char smem[16384 + 49152];
  char* As = smem;           // fp32 [64 rows][16 sq of 16B], swizzle sq^(row&15)
  char* Bs = smem + 16384;   // bf16 [384 rows][8 oct], swizzle oct^(row&7)
  const int tid = threadIdx.x, wid = tid >> 6, lane = tid & 63;
  const int m = lane & 15, quad = lane >> 4;
  const int row0 = blockIdx.x * 64;
  const int wm = (wid >> 1) * 32, wn = (wid & 1) * 192;
  float4v acc[2][12] = {};
  for (int kc = 0; kc < 512; kc += 64) {
#pragma unroll
    for (int u = 0; u < 4; ++u) {  // A: region = 4 rows x 16 sq (1KB)
      const int r0 = (wid * 4 + u) * 4;
      const int row = r0 + (lane >> 4);
      const int sqg = (lane & 15) ^ (row & 15);
      gll16(x + (size_t)(row0 + row) * 512 + kc + sqg * 4, As + r0 * 256);
    }
#pragma unroll
    for (int u = 0; u < 12; ++u) {  // B: region = 8 rows x 8 oct (1KB)
      const int r0 = (wid * 12 + u) * 8;
      const int row = r0 + (lane >> 3);
      const int og = (lane & 7) ^ (row & 7);
      gll16(wAll + (size_t)row * 512 + kc + og * 8, Bs + r0 * 128);
    }
    __syncthreads();
#pragma unroll
    for (int kk = 0; kk < 64; kk += 32) {
      short8 af[2];
#pragma unroll
      for (int i = 0; i < 2; ++i) {
        const int row = wm + i * 16 + m;
        const int sq0 = (kk >> 2) + quad * 2;
        float4v lo = *(const float4v*)(As + row * 256 + ((sq0 ^ m) * 16));
        float4v hi = *(const float4v*)(As + row * 256 + (((sq0 + 1) ^ m) * 16));
        short8 a;
        a[0] = __builtin_bit_cast(short, __float2bfloat16(lo[0]));
        a[1] = __builtin_bit_cast(short, __float2bfloat16(lo[1]));
        a[2] = __builtin_bit_cast(short, __float2bfloat16(lo[2]));
        a[3] = __builtin_bit_cast(short, __float2bfloat16(lo[3]));
        a[4] = __builtin_bit_cast(short, __float2bfloat16(hi[0]));
        a[5] = __builtin_bit_cast(short, __float2bfloat16(hi[1]));
        a[6] = __builtin_bit_cast(short, __float2bfloat16(hi[2]));
        a[7] = __builtin_bit_cast(short, __float2bfloat16(hi[3]));
        af[i] = a;
      }
      const int oct = (kk >> 3) + quad;
#pragma unroll
      for (int j = 0; j < 12; ++j) {
        short8 bf = *fragp(Bs, wn + j * 16 + m, oct);
#pragma unroll
        for (int i = 0; i < 2; ++i) acc[i][j] = mfma16(af[i], bf, acc[i][j]);
      }
    }
    __syncthreads();
  }
#pragma unroll
  for (int i = 0; i < 2; ++i)
#pragma unroll
    for (int j = 0; j < 12; ++j)
#pragma unroll
      for (int r = 0; r < 4; ++r)
        pgf[(size_t)(row0 + wm + i * 16 + quad * 4 + r) * 384 + wn + j * 16 + m] =
            __float2bfloat16(acc[i][j][r]);
}

// phi_p[b][p][c] = max 2x2 of pgf[b,h,w,64+c]
__global__ __launch_bounds__(256) void k_pool_phi(const __hip_bfloat16* __restrict__ pg,
                                                  __hip_bfloat16* __restrict__ phi_p) {
  int idx = blockIdx.x * 256 + threadIdx.x;  // 524288
  int c = idx & 63;
  int p = (idx >> 6) & 1023;
  int b = idx >> 16;
  int ph = p >> 5, pw = p & 31;
  size_t base = ((size_t)b * 4096 + ph * 128 + pw * 2) * kNP + 64 + c;
  float v0 = __bfloat162float(pg[base]);
  float v1 = __bfloat162float(pg[base + kNP]);
  float v2 = __bfloat162float(pg[base + kNP * 64]);
  float v3 = __bfloat162float(pg[base + kNP * 64 + kNP]);
  phi_p[idx] = __float2bfloat16(fmaxf(fmaxf(v0, v1), fmaxf(v2, v3)));
}

// gT[b][v][p] = max 2x2 of pgf[b,h,w,128+v]
__global__ __launch_bounds__(256) void k_pool_gT(const __hip_bfloat16* __restrict__ pg,
                                                 __hip_bfloat16* __restrict__ gT) {
  __shared__ __hip_bfloat16 t[64][65];
  const int p0 = blockIdx.x * 64, v0 = blockIdx.y * 64, b = blockIdx.z;
#pragma unroll
  for (int it = 0; it < 16; ++it) {
    int li = it * 256 + threadIdx.x;
    int pp = li >> 6, v = li & 63;
    int p = p0 + pp;
    int ph = p >> 5, pw = p & 31;
    size_t base = ((size_t)b * 4096 + ph * 128 + pw * 2) * kNP + 128 + v0 + v;
    float mv = fmaxf(
        fmaxf(__bfloat162float(pg[base]), __bfloat162float(pg[base + kNP])),
        fmaxf(__bfloat162float(pg[base + kNP * 64]), __bfloat162float(pg[base + kNP * 64 + kNP])));
    t[pp][v] = __float2bfloat16(mv);
  }
  __syncthreads();
#pragma unroll
  for (int it = 0; it < 16; ++it) {
    int li = it * 256 + threadIdx.x;
    int v = li >> 6, p = li & 63;
    gT[((size_t)b * 256 + v0 + v) * 1024 + p0 + p] = t[p][v];
  }
}

// ---- fused attention: 32 Q rows/block, 512 thr, swizzled LDS ----
// Phase1: 4 key-chunks of 256 (dbuf 2x32KB, 1 barrier/chunk).
// Phase3 (NEW): 16 p-chunks of 64, dbuf Gs 2x32KB + dbuf Ps 2x4KB,
//   stage(c+1)+writePs(c+1) overlapped with compute(c), 1 barrier/chunk.
__global__ __launch_bounds__(512) void k_fattn(
    const __hip_bfloat16* __restrict__ pgf,   // [B*4096][384], theta cols 0..63
    const __hip_bfloat16* __restrict__ phip,  // [B][1024][64]
    const __hip_bfloat16* __restrict__ gT,    // [B][256][1024]
    __hip_bfloat16* __restrict__ O) {         // [B][4096][256]
  __shared__ __align__(16) char smem[65536 + 8192 + 1024 + 128];
  char* KG = smem;               // phase1: dbuf Ks 2x32KB; phase3: dbuf Gs 2x[256][64]
  char* PQ = smem + 65536;       // phase1: Qs [32][64] 4KB; phase3: dbuf Ps 2x[32][64]
  float* pred = (float*)(smem + 65536 + 8192);            // [32][8]
  float* rowstat = (float*)(smem + 65536 + 8192 + 1024);  // [32]

  const int tid = threadIdx.x, wid = tid >> 6, lane = tid & 63;
  const int m = lane & 15, quad = lane >> 4;
  const int b = blockIdx.y, q0 = blockIdx.x * 32;

  // stage Q [32][64] (waves 0-3, 8 rows each, swizzled)
  if (wid < 4) {
    const int row = wid * 8 + (lane >> 3);
    const int og = (lane & 7) ^ (row & 7);
    gll16(pgf + (size_t)(b * kHW + q0 + row) * kNP + og * 8, PQ + wid * 8 * 128);
  }
  const __hip_bfloat16* phb = phip + (size_t)b * kP * 64;
  auto stageK = [&](int c, int buf) {
#pragma unroll
    for (int u = 0; u < 4; ++u) {
      const int r0 = wid * 32 + u * 8;
      const int row = r0 + (lane >> 3);
      const int og = (lane & 7) ^ (row & 7);
      gll16(phb + (size_t)(c * 256 + row) * 64 + og * 8, KG + buf * 32768 + r0 * 128);
    }
  };
  stageK(0, 0);
  __syncthreads();

  float4v sc[2][8] = {};
#pragma unroll
  for (int c = 0; c < 4; ++c) {
    if (c < 3) stageK(c + 1, (c + 1) & 1);
    const char* Kb = KG + (c & 1) * 32768;
    __builtin_amdgcn_s_setprio(1);
#pragma unroll
    for (int kk = 0; kk < 64; kk += 32) {
      const int oct = (kk >> 3) + quad;
      short8 a[2], bb[2];
#pragma unroll
      for (int i = 0; i < 2; ++i) a[i] = *fragp(PQ, i * 16 + m, oct);
#pragma unroll
      for (int j = 0; j < 2; ++j) bb[j] = *fragp(Kb, wid * 32 + j * 16 + m, oct);
#pragma unroll
      for (int i = 0; i < 2; ++i)
#pragma unroll
        for (int j = 0; j < 2; ++j) sc[i][c * 2 + j] = mfma16(a[i], bb[j], sc[i][c * 2 + j]);
    }
    __builtin_amdgcn_s_setprio(0);
    __syncthreads();
  }

  // ---- softmax (exact; P unnormalized, 1/sum folded into epilogue) ----
  float mx[2][4];
#pragma unroll
  for (int i = 0; i < 2; ++i)
#pragma unroll
    for (int r = 0; r < 4; ++r) {
      float v = sc[i][0][r];
#pragma unroll
      for (int s = 1; s < 8; ++s) v = fmaxf(v, sc[i][s][r]);
#pragma unroll
      for (int d = 1; d < 16; d <<= 1) v = fmaxf(v, __shfl_xor(v, d));
      mx[i][r] = v;
    }
  if (m == 0) {
#pragma unroll
    for (int i = 0; i < 2; ++i)
#pragma unroll
      for (int r = 0; r < 4; ++r) pred[(i * 16 + quad * 4 + r) * 8 + wid] = mx[i][r];
  }
  __syncthreads();
  if (tid < 32) {
    float v = pred[tid * 8];
#pragma unroll
    for (int w = 1; w < 8; ++w) v = fmaxf(v, pred[tid * 8 + w]);
    rowstat[tid] = v;
  }
  __syncthreads();
  float sm[2][4];
#pragma unroll
  for (int i = 0; i < 2; ++i)
#pragma unroll
    for (int r = 0; r < 4; ++r) {
      const float rm = rowstat[i * 16 + quad * 4 + r];
      float s = 0.f;
#pragma unroll
      for (int ss = 0; ss < 8; ++ss) {
        float e = __expf(sc[i][ss][r] - rm);
        sc[i][ss][r] = e;
        s += e;
      }
#pragma unroll
      for (int d = 1; d < 16; d <<= 1) s += __shfl_xor(s, d);
      sm[i][r] = s;
    }
  __syncthreads();
  if (m == 0) {
#pragma unroll
    for (int i = 0; i < 2; ++i)
#pragma unroll
      for (int r = 0; r < 4; ++r) pred[(i * 16 + quad * 4 + r) * 8 + wid] = sm[i][r];
  }
  __syncthreads();
  if (tid < 32) {
    float s = 0.f;
#pragma unroll
    for (int w = 0; w < 8; ++w) s += pred[tid * 8 + w];
    rowstat[tid] = 1.f / s;
  }

  // ---- PV: 16 chunks of 64 p, double-buffered Gs (2x32KB) + Ps (2x4KB) ----
  const __hip_bfloat16* gb = gT + (size_t)b * kCV * kP;
  auto stageG = [&](int cp, int buf) {
#pragma unroll
    for (int u = 0; u < 4; ++u) {  // Gs[256 v][64 p] chunk = 32KB; region 8 rows
      const int r0 = wid * 32 + u * 8;
      const int row = r0 + (lane >> 3);
      const int og = (lane & 7) ^ (row & 7);
      gll16(gb + (size_t)row * kP + cp * 64 + og * 8, KG + buf * 32768 + r0 * 128);
    }
  };
  // chunk cp's 64 keys live in waves {2*(cp&3), 2*(cp&3)+1}, score slot c=cp>>2
  auto writePs = [&](int cp, int buf) {
    if ((wid >> 1) != (cp & 3)) return;
    const int c = cp >> 2;
    char* Pb = PQ + buf * 4096;
#pragma unroll
    for (int i = 0; i < 2; ++i)
#pragma unroll
      for (int jl = 0; jl < 2; ++jl) {
        const int pl = (wid & 1) * 32 + jl * 16 + m;
#pragma unroll
        for (int r = 0; r < 4; ++r) {
          const int row = i * 16 + quad * 4 + r;
          *(__hip_bfloat16*)(Pb + row * 128 + (((pl >> 3) ^ (row & 7)) * 16) +
                             (pl & 7) * 2) = __float2bfloat16(sc[i][c * 2 + jl][r]);
        }
      }
  };

  float4v oc[2][2] = {};
  // prologue: fill buf0 (KG buf0 / PQ buf0 last read in phase1, already barriered)
  stageG(0, 0);
  writePs(0, 0);
  __syncthreads();
  for (int cp = 0; cp < 16; ++cp) {
    const int cur = cp & 1;
    if (cp < 15) {  // overlap next-chunk staging with this chunk's MFMA
      stageG(cp + 1, cur ^ 1);
      writePs(cp + 1, cur ^ 1);
    }
    const char* Gb = KG + cur * 32768;
    const char* Pb = PQ + cur * 4096;
    __builtin_amdgcn_s_setprio(1);
#pragma unroll
    for (int kk = 0; kk < 64; kk += 32) {
      const int oct = (kk >> 3) + quad;
      short8 a[2], bb[2];
#pragma unroll
      for (int i = 0; i < 2; ++i) a[i] = *fragp(Pb, i * 16 + m, oct);
#pragma unroll
      for (int j = 0; j < 2; ++j) bb[j] = *fragp(Gb, wid * 32 + j * 16 + m, oct);
#pragma unroll
      for (int i = 0; i < 2; ++i)
#pragma unroll
        for (int j = 0; j < 2; ++j) oc[i][j] = mfma16(a[i], bb[j], oc[i][j]);
    }
    __builtin_amdgcn_s_setprio(0);
    __syncthreads();  // drains this iter's gll16 (vmcnt) + orders buf reuse
  }
#pragma unroll
  for (int i = 0; i < 2; ++i)
#pragma unroll
    for (int j = 0; j < 2; ++j)
#pragma unroll
      for (int r = 0; r < 4; ++r) {
        const int row = i * 16 + quad * 4 + r;
        O[((size_t)b * kHW + q0 + row) * kCV + wid * 32 + j * 16 + m] =
            __float2bfloat16(oc[i][j][r] * rowstat[row]);
      }
}

// ---- out = x + gamma * (O @ w_o), tile 128x128, dbuf, swizzled ----
__global__ __launch_bounds__(256) void k_out(const __hip_bfloat16* __restrict__ A,
                                             const __hip_bfloat16* __restrict__ Bw,
                                             const float* __restrict__ x,
                                             const float* __restrict__ gamma,
                                             float* __restrict__ out) {
  __shared__ __align__(16) char smem[4 * 16384];  // As[2] then Bs[2]
  const int tid = threadIdx.x, wid = tid >> 6, lane = tid & 63;
  const int m = lane & 15, quad = lane >> 4;
  const int row0 = blockIdx.x * 128, col0 = blockIdx.y * 128;
  const int wm = (wid >> 1) * 64, wn = (wid & 1) * 64;
  float4v acc[4][4] = {};
  auto stage = [&](int t, int buf) {
    const int kc = t * 64;
#pragma unroll
    for (int u = 0; u < 4; ++u) {
      const int r0 = (wid * 4 + u) * 8;
      const int row = r0 + (lane >> 3);
      const int og = (lane & 7) ^ (row & 7);
      gll16(A + (size_t)(row0 + row) * 256 + kc + og * 8, smem + buf * 16384 + r0 * 128);
      gll16(Bw + (size_t)(col0 + row) * 256 + kc + og * 8,
            smem + 32768 + buf * 16384 + r0 * 128);
    }
  };
  stage(0, 0);
  __syncthreads();
#pragma unroll
  for (int t = 0; t < 4; ++t) {
    if (t < 3) stage(t + 1, (t + 1) & 1);
    const char* Ab = smem + (t & 1) * 16384;
    const char* Bb = smem + 32768 + (t & 1) * 16384;
    __builtin_amdgcn_s_setprio(1);
#pragma unroll
    for (int kk = 0; kk < 64; kk += 32) {
      const int oct = (kk >> 3) + quad;
      short8 af[4], bf[4];
#pragma unroll
      for (int i = 0; i < 4; ++i) af[i] = *fragp(Ab, wm + i * 16 + m, oct);
#pragma unroll
      for (int j = 0; j < 4; ++j) bf[j] = *fragp(Bb, wn + j * 16 + m, oct);
#pragma unroll
      for (int i = 0; i < 4; ++i)
#pragma unroll
        for (int j = 0; j < 4; ++j) acc[i][j] = mfma16(af[i], bf[j], acc[i][j]);
    }
    __builtin_amdgcn_s_setprio(0);
    __syncthreads();
  }
  const float g = gamma[0];
#pragma unroll
  for (int i = 0; i < 4; ++i)
#pragma unroll
    for (int j = 0; j < 4; ++j) {
      const int cc = col0 + wn + j * 16 + m;
      const int rb = row0 + wm + i * 16 + quad * 4;
#pragma unroll
      for (int r = 0; r < 4; ++r) {
        const size_t idx = (size_t)(rb + r) * 512 + cc;
        out[idx] = x[idx] + g * acc[i][j][r];
      }
    }
}

extern "C" void kernel_launch(void* const* d_in, const int* in_sizes, int n_in,
                              void* d_out, int out_size, void* d_ws, size_t ws_size,
                              hipStream_t stream) {
  (void)in_sizes; (void)n_in; (void)out_size; (void)ws_size;
  const float* x     = (const float*)d_in[0];
  const float* wt    = (const float*)d_in[1];
  const float* wphi  = (const float*)d_in[2];
  const float* wg    = (const float*)d_in[3];
  const float* wo    = (const float*)d_in[4];
  const float* gamma = (const float*)d_in[5];
  float* out = (float*)d_out;

  char* ws = (char*)d_ws;
  __hip_bfloat16* wAll = (__hip_bfloat16*)(ws);              //    393,216
  __hip_bfloat16* woT  = (__hip_bfloat16*)(ws + 393216);     //    262,144
  __hip_bfloat16* pgf  = (__hip_bfloat16*)(ws + 655360);     // 25,165,824
  __hip_bfloat16* phip = (__hip_bfloat16*)(ws + 25821184);   //  1,048,576
  __hip_bfloat16* gT   = (__hip_bfloat16*)(ws + 26869760);   //  4,194,304
  __hip_bfloat16* O    = (__hip_bfloat16*)(ws + 31064064);   // 16,777,216  (total 47.8MB)

  k_pack_w<<<1280, 256, 0, stream>>>(wt, wphi, wg, wo, wAll, woT);
  k_proj<<<512, 256, 0, stream>>>(x, wAll, pgf);
  k_pool_phi<<<2048, 256, 0, stream>>>(pgf, phip);
  k_pool_gT<<<dim3(16, 4, 8), 256, 0, stream>>>(pgf, gT);
  k_fattn<<<dim3(kHW / 32, kB), 512, 0, stream>>>(pgf, phip, gT, O);
  k_out<<<dim3(256, 4), 256, 0, stream>>>(O, woT, x, gamma, out);
}